// Round 4
// baseline (499.072 us; speedup 1.0000x reference)
//
#include <hip/hip_runtime.h>
#include <stdint.h>

// ---------------- problem constants ----------------
#define SDIM   128
#define SHY    7
#define SHX    14
#define CELLS  (SDIM*SDIM*SDIM)   // 2097152
#define COUT   64
#define NLINES (SDIM*SDIM)        // 16384 (x,y) z-lines
#define LINEW  136                // halo line: z=-1..134 (129 used, padded)

typedef float v2f __attribute__((ext_vector_type(2)));

// ws layout (bytes):
//   g         : [0, CELLS*4)                 8 MB  float
//   mask      : [CELLS*4, CELLS*5)           2 MB  u8
//   line_cnt  : [CELLS*5, +64K)              u32[NLINES]
//   line_rank : [CELLS*5+64K, +64K)          u32[NLINES]
//   total U   : [CELLS*5+128K, +4)           u32

// ---------------------------------------------------------------
__global__ void points_kernel(const int* __restrict__ idx,
                              const float* __restrict__ feat,
                              float* __restrict__ g,
                              unsigned char* __restrict__ mask, int n)
{
    int i = blockIdx.x * blockDim.x + threadIdx.x;
    if (i >= n) return;
    int x = idx[3*i+0], y = idx[3*i+1], z = idx[3*i+2];
    float f = feat[i];
    atomicAdd(&g[(x<<SHX)|(y<<SHY)|z], f);
    #pragma unroll
    for (int a = -1; a <= 1; ++a)
    #pragma unroll
    for (int b = -1; b <= 1; ++b)
    #pragma unroll
    for (int c = -1; c <= 1; ++c) {
        int nx = x+a, ny = y+b, nz = z+c;
        if ((unsigned)nx < SDIM && (unsigned)ny < SDIM && (unsigned)nz < SDIM)
            mask[(nx<<SHX)|(ny<<SHY)|nz] = 1;   // idempotent store, race-safe
    }
}

// ---------------------------------------------------------------
// one thread per z-line: popcount its 128 mask bytes (each 0/1)
__global__ void line_count_kernel(const unsigned char* __restrict__ mask,
                                  unsigned int* __restrict__ cnt)
{
    int line = blockIdx.x * blockDim.x + threadIdx.x;   // 0..16383
    const uint4* p = (const uint4*)(mask + (size_t)line * SDIM);
    unsigned s = 0;
    #pragma unroll
    for (int k = 0; k < 8; ++k) {
        uint4 v = p[k];
        s += __popc(v.x) + __popc(v.y) + __popc(v.z) + __popc(v.w);
    }
    cnt[line] = s;
}

// exclusive scan of 16384 line counts; single block of 1024, 16 lines/thread
#define SCANT 1024
#define LPT   (NLINES/SCANT)   // 16
__global__ void line_scan_kernel(const unsigned int* __restrict__ cnt,
                                 unsigned int* __restrict__ rank,
                                 unsigned int* __restrict__ total)
{
    __shared__ unsigned int lds[SCANT];
    int t = threadIdx.x;
    unsigned int local[LPT];
    unsigned int s = 0;
    #pragma unroll
    for (int k = 0; k < LPT; ++k) { local[k] = cnt[t*LPT + k]; s += local[k]; }
    lds[t] = s; __syncthreads();
    for (int off = 1; off < SCANT; off <<= 1) {
        unsigned int add = (t >= off) ? lds[t-off] : 0u;
        __syncthreads();
        lds[t] += add;
        __syncthreads();
    }
    unsigned int run = lds[t] - s;      // exclusive prefix of this thread's chunk
    #pragma unroll
    for (int k = 0; k < LPT; ++k) { rank[t*LPT + k] = run; run += local[k]; }
    if (t == SCANT-1) *total = lds[t];
}

// ---------------------------------------------------------------
// one block per (x,y) line. Stage 9 neighbor z-lines of g in LDS, compute
// ranks via ballot prefix, then 4 waves; each wave covers z in
// [zb, zb+32) as 16 packed steps: acc2 = {row z, row z+16}.
// Taps come from a 3-deep sliding window of ds_read2-paired broadcasts;
// FMAs are v_pk_fma_f32 (2 rows per instr).
__global__ __launch_bounds__(256)
void conv_line_kernel(const float* __restrict__ g,
                      const unsigned char* __restrict__ mask,
                      const unsigned int* __restrict__ line_rank,
                      const float* __restrict__ w,        // [27][64]
                      float* __restrict__ out_coords,     // [rows][3]
                      float* __restrict__ out_feat)       // [rows][64]
{
    __shared__ float gl[9][LINEW];
    __shared__ unsigned int rankz[SDIM];
    __shared__ unsigned int w0cnt;

    const int t   = threadIdx.x;
    const int bid = blockIdx.x;          // = x*128 + y
    const int x = bid >> 7, y = bid & 127;

    // ---- stage 9 halo lines (zero-filled at boundaries) ----
    for (int j = t; j < 9*LINEW; j += 256) {
        int l = j / LINEW, i = j - l*LINEW;
        int xx = x + (l/3) - 1, yy = y + (l%3) - 1, zz = i - 1;
        float v = 0.f;
        if ((unsigned)xx < SDIM && (unsigned)yy < SDIM && (unsigned)zz < SDIM)
            v = g[(xx<<SHX)|(yy<<SHY)|zz];
        gl[l][i] = v;
    }

    // ---- per-cell ranks: ballot prefix over the line's 128 mask bytes ----
    unsigned int pre = 0; int m = 0;
    if (t < SDIM) {
        m = mask[((size_t)bid << SHY) | t];
        unsigned long long b = __ballot(m != 0);
        int lane = t & 63;
        pre = __popcll(b & ((1ull << lane) - 1ull));
        if (t == 63) w0cnt = __popcll(b);
    }
    __syncthreads();                     // covers gl fill + w0cnt
    if (t < SDIM) {
        if (t >= 64) pre += w0cnt;
        rankz[t] = m ? (line_rank[bid] + pre) : 0xFFFFFFFFu;
    }
    __syncthreads();

    // ---- weights: lane = channel, packed {w,w} ----
    const int lane = t & 63;
    v2f wpk[27];
    #pragma unroll
    for (int k = 0; k < 27; ++k) {
        float wv = w[k*COUT + lane];
        wpk[k] = (v2f){wv, wv};
    }

    const int zb = (t >> 6) << 5;        // 0,32,64,96 per wave
    const float fx = (float)x, fy = (float)y;

    // sliding window: win[l][j] holds pair {gl[l][zb+q], gl[l][zb+q+16]}
    v2f win[9][3];
    #pragma unroll
    for (int l = 0; l < 9; ++l)
        #pragma unroll
        for (int d = 0; d < 2; ++d)
            win[l][d] = (v2f){ gl[l][zb + d], gl[l][zb + d + 16] };

    #pragma unroll
    for (int s = 0; s < 16; ++s) {
        #pragma unroll
        for (int l = 0; l < 9; ++l)
            win[l][(s + 2) % 3] = (v2f){ gl[l][zb + s + 2], gl[l][zb + s + 18] };

        v2f acc = (v2f){0.f, 0.f};
        #pragma unroll
        for (int l = 0; l < 9; ++l)
            #pragma unroll
            for (int d = 0; d < 3; ++d)
                acc = __builtin_elementwise_fma(wpk[l*3 + d], win[l][(s + d) % 3], acc);

        const int z0 = zb + s, z1 = zb + s + 16;
        unsigned int r0 = rankz[z0], r1 = rankz[z1];
        if (r0 != 0xFFFFFFFFu) {
            out_feat[(size_t)r0*COUT + lane] = acc.x;
            if (lane < 3)
                out_coords[(size_t)r0*3 + lane] = (lane==0) ? fx : ((lane==1) ? fy : (float)z0);
        }
        if (r1 != 0xFFFFFFFFu) {
            out_feat[(size_t)r1*COUT + lane] = acc.y;
            if (lane < 3)
                out_coords[(size_t)r1*3 + lane] = (lane==0) ? fx : ((lane==1) ? fy : (float)z1);
        }
    }
}

// ---------------------------------------------------------------
// rows >= U: coords = 128.0, feat = 0. Grid-stride, float4 for feat.
__global__ void pad_kernel(const unsigned int* __restrict__ totalp,
                           float* __restrict__ out_coords,
                           float* __restrict__ out_feat, int rows)
{
    unsigned int U = *totalp;
    size_t gid  = (size_t)blockIdx.x * blockDim.x + threadIdx.x;
    size_t nthr = (size_t)gridDim.x * blockDim.x;

    float4* f4 = (float4*)out_feat;      // 16 float4 per row
    const float4 z4 = make_float4(0.f, 0.f, 0.f, 0.f);
    for (size_t i = (size_t)U*16 + gid; i < (size_t)rows*16; i += nthr) f4[i] = z4;

    for (size_t i = (size_t)U*3 + gid; i < (size_t)rows*3; i += nthr) out_coords[i] = 128.f;
}

// ---------------------------------------------------------------
extern "C" void kernel_launch(void* const* d_in, const int* in_sizes, int n_in,
                              void* d_out, int out_size, void* d_ws, size_t ws_size,
                              hipStream_t stream)
{
    const int*   indices  = (const int*)d_in[0];
    const float* features = (const float*)d_in[1];
    const float* weights  = (const float*)d_in[2];

    const int n    = in_sizes[1];             // features is (N,1)
    const int rows = out_size / (3 + COUT);   // uniq rows = N*27

    float* out_coords = (float*)d_out;                  // [rows][3]
    float* out_feat   = out_coords + (size_t)3 * rows;  // [rows][64]

    char* ws = (char*)d_ws;
    float*         g         = (float*)ws;
    unsigned char* mask      = (unsigned char*)(ws + (size_t)CELLS*4);
    unsigned int*  line_cnt  = (unsigned int*)(ws + (size_t)CELLS*5);
    unsigned int*  line_rank = (unsigned int*)(ws + (size_t)CELLS*5 + 65536);
    unsigned int*  total     = (unsigned int*)(ws + (size_t)CELLS*5 + 131072);

    hipMemsetAsync(g, 0, (size_t)CELLS*5, stream);   // zero g (8MB) + mask (2MB)

    points_kernel<<<(n + 255)/256, 256, 0, stream>>>(indices, features, g, mask, n);
    line_count_kernel<<<NLINES/256, 256, 0, stream>>>(mask, line_cnt);
    line_scan_kernel<<<1, SCANT, 0, stream>>>(line_cnt, line_rank, total);
    conv_line_kernel<<<NLINES, 256, 0, stream>>>(g, mask, line_rank, weights,
                                                 out_coords, out_feat);
    pad_kernel<<<1024, 256, 0, stream>>>(total, out_coords, out_feat, rows);
}